// Round 2
// baseline (363.993 us; speedup 1.0000x reference)
//
#include <hip/hip_runtime.h>

// ---------------------------------------------------------------------------
// DeformableTransformer encoder layer, MI355X (gfx950).
// R10: GEMMs were latency-bound (MfmaUtil 13%, 4x A-overfetch). Added
// (a) XCD-chunked bijective tile swizzle (col-tile fastest within chunk) so
// each XCD's A row-band stays in its 4MB L2 -- applied to all GEMMs and to
// sample_kernel's bs blocks; (b) depth-2 register prefetch in GEMM_CORE
// (K now a compile-time template arg; two named register sets, static
// indexing). Sample/LN/add_q/prep unchanged (R9 forms).
// ---------------------------------------------------------------------------

typedef __bf16 bf16_t;
typedef __bf16 bf16x8 __attribute__((ext_vector_type(8)));
typedef __bf16 bf16x4 __attribute__((ext_vector_type(4)));
typedef float  f32x2  __attribute__((ext_vector_type(2)));
typedef float  f32x4  __attribute__((ext_vector_type(4)));
typedef float  f32x16 __attribute__((ext_vector_type(16)));

#define M_ROWS 17000   // B*S
#define S_LEN  8500

// ---------------------------------------------------------------- helpers
__device__ inline void store_c(float* p, float v)  { *p = v; }
__device__ inline void store_c(bf16_t* p, float v) { *p = (bf16_t)v; }

__device__ inline float4 load4f(const float* p)  { return *(const float4*)p; }
__device__ inline float4 load4f(const bf16_t* p) {
    bf16x4 v = *(const bf16x4*)p;
    return make_float4((float)v[0], (float)v[1], (float)v[2], (float)v[3]);
}

__device__ inline void pk_fma(f32x2& a, f32x2 x, f32x2 y) {
    asm("v_pk_fma_f32 %0, %1, %2, %0" : "+v"(a) : "v"(x), "v"(y));
}

// bijective XCD-chunked swizzle (m204 form): contiguous result-range per XCD
__device__ inline int swz_flat() {
    int o   = blockIdx.x + gridDim.x * blockIdx.y;
    int nwg = gridDim.x * gridDim.y;
    int q = nwg >> 3, r = nwg & 7;
    int xcd = o & 7, s = o >> 3;
    return (xcd < r ? xcd * (q + 1) : r * (q + 1) + (xcd - r) * q) + s;
}

// ---------------------------------------------------------------- prep
// z = 0..5: transpose f32 [K][N] -> bf16 [N][K] (32x32 tiles);  z = 6: bias concat
__global__ __launch_bounds__(256)
void prep_kernel(const float* __restrict__ w_val, const float* __restrict__ w_off,
                 const float* __restrict__ w_attn, const float* __restrict__ w_out,
                 const float* __restrict__ w1, const float* __restrict__ w2,
                 const float* __restrict__ b_off, const float* __restrict__ b_attn,
                 bf16_t* __restrict__ wt_val, bf16_t* __restrict__ wt_oa,
                 bf16_t* __restrict__ wt_out, bf16_t* __restrict__ wt_w1,
                 bf16_t* __restrict__ wt_w2, float* __restrict__ bias_oa) {
    int z = blockIdx.z;
    if (z == 6) {
        if (blockIdx.x == 0 && blockIdx.y == 0) {
            for (int i = threadIdx.x; i < 384; i += 256)
                bias_oa[i] = (i < 256) ? b_off[i] : b_attn[i - 256];
        }
        return;
    }
    const float* in; bf16_t* out; int K, N;
    switch (z) {
        case 0: in = w_val;  out = wt_val;                     K = 512;  N = 512;  break;
        case 1: in = w_off;  out = wt_oa;                      K = 512;  N = 256;  break;
        case 2: in = w_attn; out = wt_oa + (size_t)256 * 512;  K = 512;  N = 128;  break;
        case 3: in = w_out;  out = wt_out;                     K = 512;  N = 512;  break;
        case 4: in = w1;     out = wt_w1;                      K = 512;  N = 1024; break;
        default: in = w2;    out = wt_w2;                      K = 1024; N = 512;  break;
    }
    int k0 = blockIdx.x * 32, n0 = blockIdx.y * 32;
    if (k0 >= K || n0 >= N) return;
    __shared__ float s[32][33];
    int tx = threadIdx.x & 31, ty = threadIdx.x >> 5;   // ty 0..7
    #pragma unroll
    for (int i = 0; i < 4; i++)
        s[ty + 8 * i][tx] = in[(size_t)(k0 + ty + 8 * i) * N + n0 + tx];
    __syncthreads();
    #pragma unroll
    for (int i = 0; i < 4; i++)
        out[(size_t)(n0 + ty + 8 * i) * K + k0 + tx] = (bf16_t)s[tx][ty + 8 * i];
}

// ---------------------------------------------------------------- q = src+pos
__global__ __launch_bounds__(256)
void add_q_kernel(const float* __restrict__ a, const float* __restrict__ b,
                  bf16_t* __restrict__ q, bf16_t* __restrict__ src_bf, int n4) {
    int i = blockIdx.x * 256 + threadIdx.x;
    if (i >= n4) return;
    float4 av = *(const float4*)(a + (size_t)i * 4);
    float4 bv = *(const float4*)(b + (size_t)i * 4);
    bf16x4 sv, ov;
    sv[0] = (bf16_t)av.x; sv[1] = (bf16_t)av.y; sv[2] = (bf16_t)av.z; sv[3] = (bf16_t)av.w;
    ov[0] = (bf16_t)(av.x + bv.x);
    ov[1] = (bf16_t)(av.y + bv.y);
    ov[2] = (bf16_t)(av.z + bv.z);
    ov[3] = (bf16_t)(av.w + bv.w);
    *(bf16x4*)(q      + (size_t)i * 4) = ov;
    *(bf16x4*)(src_bf + (size_t)i * 4) = sv;
}

// ---------------------------------------------------------------- GEMM core
// 128x128 tile, BK=32, dbuf LDS, 32x32x16 MFMA, depth-2 register prefetch.
// Caller must define: row0, col0 (swizzled) and As/Bs LDS. K_DIM compile-time.
#define MMA_PHASE(CUR)                                                             \
    _Pragma("unroll")                                                              \
    for (int kh = 0; kh < 2; kh++) {                                               \
        bf16x8 a0 = *(const bf16x8*)&As[CUR][wr + l31     ][kh * 16 + lh8];        \
        bf16x8 a1 = *(const bf16x8*)&As[CUR][wr + 32 + l31][kh * 16 + lh8];        \
        bf16x8 b0 = *(const bf16x8*)&Bs[CUR][wc + l31     ][kh * 16 + lh8];        \
        bf16x8 b1 = *(const bf16x8*)&Bs[CUR][wc + 32 + l31][kh * 16 + lh8];        \
        acc[0][0] = __builtin_amdgcn_mfma_f32_32x32x16_bf16(a0, b0, acc[0][0], 0, 0, 0); \
        acc[0][1] = __builtin_amdgcn_mfma_f32_32x32x16_bf16(a0, b1, acc[0][1], 0, 0, 0); \
        acc[1][0] = __builtin_amdgcn_mfma_f32_32x32x16_bf16(a1, b0, acc[1][0], 0, 0, 0); \
        acc[1][1] = __builtin_amdgcn_mfma_f32_32x32x16_bf16(a1, b1, acc[1][1], 0, 0, 0); \
    }

#define GEMM_CORE(A_PTR, WT_PTR, K_DIM, EPILOGUE)                                  \
    const int tid  = threadIdx.x;                                                  \
    const int wave = tid >> 6;                                                     \
    const int lane = tid & 63;                                                     \
    const int l31  = lane & 31;                                                    \
    const int lh8  = (lane >> 5) * 8;                                              \
    const int wr   = (wave >> 1) * 64;                                             \
    const int wc   = (wave & 1) * 64;                                              \
    const int sr = tid >> 2;                                                       \
    const int sc = (tid & 3) * 8;                                                  \
    const bf16_t* gA0 = A_PTR  + (size_t)min(row0 + sr,      M_ROWS - 1) * (K_DIM) + sc; \
    const bf16_t* gA1 = A_PTR  + (size_t)min(row0 + sr + 64, M_ROWS - 1) * (K_DIM) + sc; \
    const bf16_t* gB0 = WT_PTR + (size_t)(col0 + sr) * (K_DIM) + sc;               \
    const bf16_t* gB1 = WT_PTR + (size_t)(col0 + sr + 64) * (K_DIM) + sc;          \
    f32x16 acc[2][2];                                                              \
    _Pragma("unroll")                                                              \
    for (int i = 0; i < 2; i++)                                                    \
        _Pragma("unroll")                                                          \
        for (int j = 0; j < 2; j++)                                                \
            _Pragma("unroll")                                                      \
            for (int r = 0; r < 16; r++) acc[i][j][r] = 0.f;                       \
    bf16x8 paA0 = *(const bf16x8*)gA0;                                             \
    bf16x8 paA1 = *(const bf16x8*)gA1;                                             \
    bf16x8 pbA0 = *(const bf16x8*)gB0;                                             \
    bf16x8 pbA1 = *(const bf16x8*)gB1;                                             \
    bf16x8 paB0 = *(const bf16x8*)(gA0 + 32);                                      \
    bf16x8 paB1 = *(const bf16x8*)(gA1 + 32);                                      \
    bf16x8 pbB0 = *(const bf16x8*)(gB0 + 32);                                      \
    bf16x8 pbB1 = *(const bf16x8*)(gB1 + 32);                                      \
    const int nIter = (K_DIM) >> 5;                                                \
    for (int it = 0; it < nIter; it += 2) {                                        \
        *(bf16x8*)&As[0][sr][sc]      = paA0;                                      \
        *(bf16x8*)&As[0][sr + 64][sc] = paA1;                                      \
        *(bf16x8*)&Bs[0][sr][sc]      = pbA0;                                      \
        *(bf16x8*)&Bs[0][sr + 64][sc] = pbA1;                                      \
        __syncthreads();                                                           \
        if (it + 2 < nIter) {                                                      \
            const int ko = (it + 2) << 5;                                          \
            paA0 = *(const bf16x8*)(gA0 + ko);                                     \
            paA1 = *(const bf16x8*)(gA1 + ko);                                     \
            pbA0 = *(const bf16x8*)(gB0 + ko);                                     \
            pbA1 = *(const bf16x8*)(gB1 + ko);                                     \
        }                                                                          \
        MMA_PHASE(0)                                                               \
        *(bf16x8*)&As[1][sr][sc]      = paB0;                                      \
        *(bf16x8*)&As[1][sr + 64][sc] = paB1;                                      \
        *(bf16x8*)&Bs[1][sr][sc]      = pbB0;                                      \
        *(bf16x8*)&Bs[1][sr + 64][sc] = pbB1;                                      \
        __syncthreads();                                                           \
        if (it + 3 < nIter) {                                                      \
            const int ko = (it + 3) << 5;                                          \
            paB0 = *(const bf16x8*)(gA0 + ko);                                     \
            paB1 = *(const bf16x8*)(gA1 + ko);                                     \
            pbB0 = *(const bf16x8*)(gB0 + ko);                                     \
            pbB1 = *(const bf16x8*)(gB1 + ko);                                     \
        }                                                                          \
        MMA_PHASE(1)                                                               \
    }                                                                              \
    EPILOGUE

// generic GEMM: C[M,N] = A @ Wt^T + bias, optional ReLU. KD compile-time.
template<typename OT, bool RELU, int KD>
__global__ __launch_bounds__(256)
void gemm128_kernel(const bf16_t* __restrict__ A, const bf16_t* __restrict__ Wt,
                    const float* __restrict__ bias, OT* __restrict__ Cout, int N) {
    __shared__ bf16_t As[2][128][40];
    __shared__ bf16_t Bs[2][128][40];
    const int wg = swz_flat();
    const int NY = gridDim.y;
    const int row0 = (wg / NY) * 128;
    const int col0 = (wg % NY) * 128;
    GEMM_CORE(A, Wt, KD,
        {
            _Pragma("unroll")
            for (int i = 0; i < 2; i++)
                _Pragma("unroll")
                for (int j = 0; j < 2; j++) {
                    int col = col0 + wc + j * 32 + l31;
                    float bcol = bias[col];
                    _Pragma("unroll")
                    for (int reg = 0; reg < 16; reg++) {
                        int row = row0 + wr + i * 32 + (reg & 3) + 8 * (reg >> 2) + 4 * (lane >> 5);
                        if (row < M_ROWS) {
                            float v = acc[i][j][reg] + bcol;
                            if (RELU) v = fmaxf(v, 0.f);
                            store_c(Cout + (size_t)row * N + col, v);
                        }
                    }
                }
        }
    )
}

// merged value (+src_bf A) and oa (+q A) GEMM: col-tile<4 -> value, else oa
__global__ __launch_bounds__(256)
void gemm_voa_kernel(const bf16_t* __restrict__ src_bf, const bf16_t* __restrict__ q,
                     const bf16_t* __restrict__ wt_val, const bf16_t* __restrict__ wt_oa,
                     const float* __restrict__ b_val, const float* __restrict__ bias_oa,
                     bf16_t* __restrict__ value, float* __restrict__ oa) {
    __shared__ bf16_t As[2][128][40];
    __shared__ bf16_t Bs[2][128][40];
    const int wg = swz_flat();
    const int by = wg % 7;
    const bool isV  = by < 4;
    const int col0  = (isV ? by : by - 4) * 128;
    const int row0  = (wg / 7) * 128;
    const bf16_t* Ap  = isV ? src_bf : q;
    const bf16_t* Wp  = isV ? wt_val : wt_oa;
    const float* bp   = isV ? b_val : bias_oa;
    GEMM_CORE(Ap, Wp, 512,
        {
            _Pragma("unroll")
            for (int i = 0; i < 2; i++)
                _Pragma("unroll")
                for (int j = 0; j < 2; j++) {
                    int col = col0 + wc + j * 32 + l31;
                    float bcol = bp[col];
                    _Pragma("unroll")
                    for (int reg = 0; reg < 16; reg++) {
                        int row = row0 + wr + i * 32 + (reg & 3) + 8 * (reg >> 2) + 4 * (lane >> 5);
                        if (row < M_ROWS) {
                            float v = acc[i][j][reg] + bcol;
                            if (isV) value[(size_t)row * 512 + col] = (bf16_t)v;
                            else     oa[(size_t)row * 384 + col] = v;
                        }
                    }
                }
        }
    )
}

// ---------------------------------------------------------------- sampling (R9)
// 1 wave per bs-row. lane = (h = lane>>3, sub = lane&7). Softmax fused.
__global__ __launch_bounds__(256)
void sample_kernel(const bf16_t* __restrict__ value, const float* __restrict__ oa,
                   bf16_t* __restrict__ out) {
    __shared__ __align__(16) int sAW[4][2][8][68];   // [wave][addr/wgt][h][c pad]
    const int wave = threadIdx.x >> 6;
    const int lane = threadIdx.x & 63;
    const int h    = lane >> 3;
    const int sub  = lane & 7;
    const int bs   = swz_flat() * 4 + wave;          // grid = 4250 exactly
    const int b    = bs / S_LEN;
    const int s    = bs - b * S_LEN;

    float rx, ry;
    if (s < 6400)      { int i = s;        const float inv = 1.f/80.f; ry = ((i/80) + 0.5f)*inv; rx = ((i%80) + 0.5f)*inv; }
    else if (s < 8000) { int i = s - 6400; const float inv = 1.f/40.f; ry = ((i/40) + 0.5f)*inv; rx = ((i%40) + 0.5f)*inv; }
    else if (s < 8400) { int i = s - 8000; const float inv = 1.f/20.f; ry = ((i/20) + 0.5f)*inv; rx = ((i%20) + 0.5f)*inv; }
    else               { int i = s - 8400; const float inv = 1.f/10.f; ry = ((i/10) + 0.5f)*inv; rx = ((i%10) + 0.5f)*inv; }

    const int WH[4]  = {80, 40, 20, 10};
    const int LST[4] = {0, 6400, 8000, 8400};
    const int ll = sub >> 1;            // both of this lane's pts share a level
    const int W  = WH[ll];
    const int LS = LST[ll];

    const float* row = oa + (size_t)bs * 384;
    float4 o4 = *(const float4*)(row + h * 32 + sub * 4);
    float2 lg = *(const float2*)(row + 256 + h * 16 + sub * 2);

    // fused softmax over 16 logits of head h (8 lanes x 2 logits, xor 1/2/4)
    float mx = fmaxf(lg.x, lg.y);
    mx = fmaxf(mx, __shfl_xor(mx, 1, 64));
    mx = fmaxf(mx, __shfl_xor(mx, 2, 64));
    mx = fmaxf(mx, __shfl_xor(mx, 4, 64));
    float e0 = __expf(lg.x - mx), e1 = __expf(lg.y - mx);
    float sm = e0 + e1;
    sm += __shfl_xor(sm, 1, 64);
    sm += __shfl_xor(sm, 2, 64);
    sm += __shfl_xor(sm, 4, 64);
    float pinv = 1.f / sm;

    #pragma unroll
    for (int t = 0; t < 2; t++) {
        float ox = t ? o4.z : o4.x;
        float oy = t ? o4.w : o4.y;
        float p  = (t ? e1 : e0) * pinv;
        float x = fmaf(rx, (float)W, ox) - 0.5f;
        float y = fmaf(ry, (float)W, oy) - 0.5f;
        float fx = floorf(x), fy = floorf(y);
        float wx = x - fx, wy = y - fy;
        int ix = (int)fx, iy = (int)fy;
        #pragma unroll
        for (int k2 = 0; k2 < 4; k2++) {
            int cx = ix + (k2 & 1);
            int cy = iy + (k2 >> 1);
            float wgt = p * ((k2 & 1) ? wx : 1.f - wx) * ((k2 >> 1) ? wy : 1.f - wy);
            if (cx < 0 || cx >= W || cy < 0 || cy >= W) wgt = 0.f;
            int xc = min(max(cx, 0), W - 1);
            int yc = min(max(cy, 0), W - 1);
            int c = sub * 8 + t * 4 + k2;        // pt = c>>2, corner = c&3
            sAW[wave][0][h][c] = LS + yc * W + xc;
            sAW[wave][1][h][c] = __float_as_int(wgt);
        }
    }
    __syncthreads();

    // main loop: lane owns (h, d-slice); all LDS reads broadcast within group
    const bf16_t* vb = value + ((size_t)b * S_LEN) * 512 + h * 64 + sub * 8;
    f32x2 a01 = {0.f, 0.f}, a23 = {0.f, 0.f}, a45 = {0.f, 0.f}, a67 = {0.f, 0.f};

    #define ACC8(V, WW) {                                                          \
        f32x2 ws; ws[0] = (WW); ws[1] = (WW);                                      \
        f32x2 pv;                                                                  \
        pv[0] = __uint_as_float((V).x << 16);                                      \
        pv[1] = __uint_as_float((V).x & 0xffff0000u); pk_fma(a01, pv, ws);         \
        pv[0] = __uint_as_float((V).y << 16);                                      \
        pv[1] = __uint_as_float((V).y & 0xffff0000u); pk_fma(a23, pv, ws);         \
        pv[0] = __uint_as_float((V).z << 16);                                      \
        pv[1] = __uint_as_float((V).z & 0xffff0000u); pk_fma(a45, pv, ws);         \
        pv[0] = __uint_as_float((V).w << 16);                                      \
        pv[1] = __uint_as_float((V).w & 0xffff0000u); pk_fma(a67, pv, ws); }

    #pragma unroll 2
    for (int c8 = 0; c8 < 64; c8 += 8) {
        int4   ia = *(const int4*)  &sAW[wave][0][h][c8];
        int4   ib = *(const int4*)  &sAW[wave][0][h][c8 + 4];
        float4 wa = *(const float4*)&sAW[wave][1][h][c8];
        float4 wb = *(const float4*)&sAW[wave][1][h][c8 + 4];
        uint4 v0 = *(const uint4*)(vb + (size_t)ia.x * 512);
        uint4 v1 = *(const uint4*)(vb + (size_t)ia.y * 512);
        uint4 v2 = *(const uint4*)(vb + (size_t)ia.z * 512);
        uint4 v3 = *(const uint4*)(vb + (size_t)ia.w * 512);
        uint4 v4 = *(const uint4*)(vb + (size_t)ib.x * 512);
        uint4 v5 = *(const uint4*)(vb + (size_t)ib.y * 512);
        uint4 v6 = *(const uint4*)(vb + (size_t)ib.z * 512);
        uint4 v7 = *(const uint4*)(vb + (size_t)ib.w * 512);
        ACC8(v0, wa.x) ACC8(v1, wa.y) ACC8(v2, wa.z) ACC8(v3, wa.w)
        ACC8(v4, wb.x) ACC8(v5, wb.y) ACC8(v6, wb.z) ACC8(v7, wb.w)
    }
    #undef ACC8

    bf16x8 ov;
    ov[0] = (bf16_t)a01[0]; ov[1] = (bf16_t)a01[1];
    ov[2] = (bf16_t)a23[0]; ov[3] = (bf16_t)a23[1];
    ov[4] = (bf16_t)a45[0]; ov[5] = (bf16_t)a45[1];
    ov[6] = (bf16_t)a67[0]; ov[7] = (bf16_t)a67[1];
    *(bf16x8*)(out + (size_t)bs * 512 + h * 64 + sub * 8) = ov;
}

// ---------------------------------------------------------------- LayerNorm
template<typename INA, typename INB, typename OT>
__global__ __launch_bounds__(256)
void ln_kernel(const INA* __restrict__ Xa, const INB* __restrict__ Xb,
               const float* __restrict__ g, const float* __restrict__ be,
               OT* __restrict__ out, int M) {
    int wave = threadIdx.x >> 6;
    int lane = threadIdx.x & 63;
    int row = blockIdx.x * 4 + wave;
    if (row >= M) return;
    size_t base = (size_t)row * 512;
    float v[8];
    float s = 0.f, sq = 0.f;
    #pragma unroll
    for (int p = 0; p < 2; p++) {
        int idx = p * 256 + lane * 4;
        float4 a4 = load4f(Xa + base + idx);
        float4 b4 = load4f(Xb + base + idx);
        float t0 = a4.x + b4.x, t1 = a4.y + b4.y, t2 = a4.z + b4.z, t3 = a4.w + b4.w;
        v[p*4+0] = t0; v[p*4+1] = t1; v[p*4+2] = t2; v[p*4+3] = t3;
        s  += t0 + t1 + t2 + t3;
        sq += t0*t0 + t1*t1 + t2*t2 + t3*t3;
    }
    #pragma unroll
    for (int off = 32; off > 0; off >>= 1) {
        s  += __shfl_xor(s, off, 64);
        sq += __shfl_xor(sq, off, 64);
    }
    float mean = s * (1.f / 512.f);
    float var  = sq * (1.f / 512.f) - mean * mean;
    float rstd = rsqrtf(var + 1e-5f);
    #pragma unroll
    for (int p = 0; p < 2; p++) {
        int idx = p * 256 + lane * 4;
        #pragma unroll
        for (int j = 0; j < 4; j++) {
            int col = idx + j;
            float o = (v[p*4+j] - mean) * rstd * g[col] + be[col];
            store_c(out + base + col, o);
        }
    }
}

// ---------------------------------------------------------------- launch
extern "C" void kernel_launch(void* const* d_in, const int* in_sizes, int n_in,
                              void* d_out, int out_size, void* d_ws, size_t ws_size,
                              hipStream_t stream) {
    const float* src    = (const float*)d_in[0];
    const float* pos    = (const float*)d_in[1];
    const float* w_off  = (const float*)d_in[2];
    const float* b_off  = (const float*)d_in[3];
    const float* w_attn = (const float*)d_in[4];
    const float* b_attn = (const float*)d_in[5];
    const float* w_val  = (const float*)d_in[6];
    const float* b_val  = (const float*)d_in[7];
    const float* w_out  = (const float*)d_in[8];
    const float* b_out  = (const float*)d_in[9];
    const float* ln1_g  = (const float*)d_in[10];
    const float* ln1_b  = (const float*)d_in[11];
    const float* w1     = (const float*)d_in[12];
    const float* b1     = (const float*)d_in[13];
    const float* w2     = (const float*)d_in[14];
    const float* b2     = (const float*)d_in[15];
    const float* ln2_g  = (const float*)d_in[16];
    const float* ln2_b  = (const float*)d_in[17];

    const int M = M_ROWS;
    char* ws = (char*)d_ws;
    size_t o = 0;
    auto alloc = [&](size_t bytes) { size_t r = o; o += (bytes + 255) & ~(size_t)255; return r; };

    size_t off_q       = alloc((size_t)M * 512 * 2);   // bf16
    size_t off_srcbf   = alloc((size_t)M * 512 * 2);   // bf16
    size_t off_value   = alloc((size_t)M * 512 * 2);   // bf16
    size_t off_sampled = alloc((size_t)M * 512 * 2);   // bf16
    size_t off_oa      = alloc((size_t)M * 384 * 4);   // f32
    size_t off_attnout = alloc((size_t)M * 512 * 2);   // bf16
    size_t off_x       = alloc((size_t)M * 512 * 2);   // bf16
    size_t off_wtval   = alloc((size_t)512 * 512 * 2);
    size_t off_wtoa    = alloc((size_t)384 * 512 * 2);
    size_t off_wtout   = alloc((size_t)512 * 512 * 2);
    size_t off_wtw1    = alloc((size_t)1024 * 512 * 2);
    size_t off_wtw2    = alloc((size_t)512 * 1024 * 2);
    size_t off_boa     = alloc((size_t)384 * 4);

    bf16_t* q        = (bf16_t*)(ws + off_q);
    bf16_t* src_bf   = (bf16_t*)(ws + off_srcbf);
    bf16_t* value    = (bf16_t*)(ws + off_value);
    bf16_t* sampled  = (bf16_t*)(ws + off_sampled);
    float*  oa       = (float*)(ws + off_oa);
    bf16_t* attn_out = (bf16_t*)(ws + off_attnout);
    bf16_t* x        = (bf16_t*)(ws + off_x);
    bf16_t* hidden   = (bf16_t*)(ws + off_sampled);   // alias: sampled+oa dead here
    bf16_t* ffn_out  = (bf16_t*)(ws + off_attnout);   // alias: attn_out dead after ln1
    bf16_t* wt_val   = (bf16_t*)(ws + off_wtval);
    bf16_t* wt_oa    = (bf16_t*)(ws + off_wtoa);
    bf16_t* wt_out   = (bf16_t*)(ws + off_wtout);
    bf16_t* wt_w1    = (bf16_t*)(ws + off_wtw1);
    bf16_t* wt_w2    = (bf16_t*)(ws + off_wtw2);
    float*  bias_oa  = (float*)(ws + off_boa);
    float*  outp     = (float*)d_out;

    prep_kernel<<<dim3(32, 32, 7), 256, 0, stream>>>(
        w_val, w_off, w_attn, w_out, w1, w2, b_off, b_attn,
        wt_val, wt_oa, wt_out, wt_w1, wt_w2, bias_oa);

    add_q_kernel<<<(M * 512 / 4 + 255) / 256, 256, 0, stream>>>(src, pos, q, src_bf, M * 512 / 4);

    const int MT = (M + 127) / 128;   // 133

    gemm_voa_kernel<<<dim3(MT, 7), 256, 0, stream>>>(src_bf, q, wt_val, wt_oa, b_val, bias_oa, value, oa);

    // softmax fused into sample_kernel (oa holds raw logits)
    sample_kernel<<<M / 4, 256, 0, stream>>>(value, oa, sampled);

    gemm128_kernel<bf16_t, false, 512><<<dim3(MT, 4), 256, 0, stream>>>(sampled, wt_out, b_out, attn_out, 512);

    ln_kernel<float, bf16_t, bf16_t><<<(M + 3) / 4, 256, 0, stream>>>(src, attn_out, ln1_g, ln1_b, x, M);

    gemm128_kernel<bf16_t, true, 512 ><<<dim3(MT, 8), 256, 0, stream>>>(x, wt_w1, b1, hidden, 1024);
    gemm128_kernel<bf16_t, false, 1024><<<dim3(MT, 4), 256, 0, stream>>>(hidden, wt_w2, b2, ffn_out, 512);

    ln_kernel<bf16_t, bf16_t, float><<<(M + 3) / 4, 256, 0, stream>>>(x, ffn_out, ln2_g, ln2_b, outp, M);
}

// Round 3
// 358.510 us; speedup vs baseline: 1.0153x; 1.0153x over previous
//
#include <hip/hip_runtime.h>

// ---------------------------------------------------------------------------
// DeformableTransformer encoder layer, MI355X (gfx950).
// R11: GEMMs were grid-starved (532 blocks = 2.1/CU -> Occupancy 11%, Mfma
// 12%). attn-out/FFN2/voa now use 128x64 tiles (1064/1064/1862 blocks,
// LDS 30KB -> 5 blocks/CU, acc 32 VGPR). Depth-2 prefetch reverted to R9
// depth-1 (R10 regression, VGPR 92->~72). Col-fastest XCD-chunked swizzle
// kept (FETCH 72->24MB proven). FFN1 keeps 128x128. Sample/LN/add_q/prep
// unchanged (R9 forms).
// ---------------------------------------------------------------------------

typedef __bf16 bf16_t;
typedef __bf16 bf16x8 __attribute__((ext_vector_type(8)));
typedef __bf16 bf16x4 __attribute__((ext_vector_type(4)));
typedef float  f32x2  __attribute__((ext_vector_type(2)));
typedef float  f32x4  __attribute__((ext_vector_type(4)));
typedef float  f32x16 __attribute__((ext_vector_type(16)));

#define M_ROWS 17000   // B*S
#define S_LEN  8500

// ---------------------------------------------------------------- helpers
__device__ inline void store_c(float* p, float v)  { *p = v; }
__device__ inline void store_c(bf16_t* p, float v) { *p = (bf16_t)v; }

__device__ inline float4 load4f(const float* p)  { return *(const float4*)p; }
__device__ inline float4 load4f(const bf16_t* p) {
    bf16x4 v = *(const bf16x4*)p;
    return make_float4((float)v[0], (float)v[1], (float)v[2], (float)v[3]);
}

__device__ inline void pk_fma(f32x2& a, f32x2 x, f32x2 y) {
    asm("v_pk_fma_f32 %0, %1, %2, %0" : "+v"(a) : "v"(x), "v"(y));
}

// bijective XCD-chunked swizzle (m204 form): contiguous result-range per XCD
__device__ inline int swz_flat() {
    int o   = blockIdx.x + gridDim.x * blockIdx.y;
    int nwg = gridDim.x * gridDim.y;
    int q = nwg >> 3, r = nwg & 7;
    int xcd = o & 7, s = o >> 3;
    return (xcd < r ? xcd * (q + 1) : r * (q + 1) + (xcd - r) * q) + s;
}

// ---------------------------------------------------------------- prep
// z = 0..5: transpose f32 [K][N] -> bf16 [N][K] (32x32 tiles);  z = 6: bias concat
__global__ __launch_bounds__(256)
void prep_kernel(const float* __restrict__ w_val, const float* __restrict__ w_off,
                 const float* __restrict__ w_attn, const float* __restrict__ w_out,
                 const float* __restrict__ w1, const float* __restrict__ w2,
                 const float* __restrict__ b_off, const float* __restrict__ b_attn,
                 bf16_t* __restrict__ wt_val, bf16_t* __restrict__ wt_oa,
                 bf16_t* __restrict__ wt_out, bf16_t* __restrict__ wt_w1,
                 bf16_t* __restrict__ wt_w2, float* __restrict__ bias_oa) {
    int z = blockIdx.z;
    if (z == 6) {
        if (blockIdx.x == 0 && blockIdx.y == 0) {
            for (int i = threadIdx.x; i < 384; i += 256)
                bias_oa[i] = (i < 256) ? b_off[i] : b_attn[i - 256];
        }
        return;
    }
    const float* in; bf16_t* out; int K, N;
    switch (z) {
        case 0: in = w_val;  out = wt_val;                     K = 512;  N = 512;  break;
        case 1: in = w_off;  out = wt_oa;                      K = 512;  N = 256;  break;
        case 2: in = w_attn; out = wt_oa + (size_t)256 * 512;  K = 512;  N = 128;  break;
        case 3: in = w_out;  out = wt_out;                     K = 512;  N = 512;  break;
        case 4: in = w1;     out = wt_w1;                      K = 512;  N = 1024; break;
        default: in = w2;    out = wt_w2;                      K = 1024; N = 512;  break;
    }
    int k0 = blockIdx.x * 32, n0 = blockIdx.y * 32;
    if (k0 >= K || n0 >= N) return;
    __shared__ float s[32][33];
    int tx = threadIdx.x & 31, ty = threadIdx.x >> 5;   // ty 0..7
    #pragma unroll
    for (int i = 0; i < 4; i++)
        s[ty + 8 * i][tx] = in[(size_t)(k0 + ty + 8 * i) * N + n0 + tx];
    __syncthreads();
    #pragma unroll
    for (int i = 0; i < 4; i++)
        out[(size_t)(n0 + ty + 8 * i) * K + k0 + tx] = (bf16_t)s[tx][ty + 8 * i];
}

// ---------------------------------------------------------------- q = src+pos
__global__ __launch_bounds__(256)
void add_q_kernel(const float* __restrict__ a, const float* __restrict__ b,
                  bf16_t* __restrict__ q, bf16_t* __restrict__ src_bf, int n4) {
    int i = blockIdx.x * 256 + threadIdx.x;
    if (i >= n4) return;
    float4 av = *(const float4*)(a + (size_t)i * 4);
    float4 bv = *(const float4*)(b + (size_t)i * 4);
    bf16x4 sv, ov;
    sv[0] = (bf16_t)av.x; sv[1] = (bf16_t)av.y; sv[2] = (bf16_t)av.z; sv[3] = (bf16_t)av.w;
    ov[0] = (bf16_t)(av.x + bv.x);
    ov[1] = (bf16_t)(av.y + bv.y);
    ov[2] = (bf16_t)(av.z + bv.z);
    ov[3] = (bf16_t)(av.w + bv.w);
    *(bf16x4*)(q      + (size_t)i * 4) = ov;
    *(bf16x4*)(src_bf + (size_t)i * 4) = sv;
}

// ---------------------------------------------------------------- GEMM cores
// 128x128 tile, BK=32, dbuf LDS + depth-1 register prefetch, 32x32x16 MFMA.
// Wave (wr,wc) computes 64x64 as 2x2 of 32x32. D: col=lane&31,
// row=(reg&3)+8*(reg>>2)+4*(lane>>5)  [m74/m101 verified].
#define GEMM_CORE(A_PTR, WT_PTR, K_DIM, EPILOGUE)                                  \
    const int tid  = threadIdx.x;                                                  \
    const int wave = tid >> 6;                                                     \
    const int lane = tid & 63;                                                     \
    const int l31  = lane & 31;                                                    \
    const int lh8  = (lane >> 5) * 8;                                              \
    const int wr   = (wave >> 1) * 64;                                             \
    const int wc   = (wave & 1) * 64;                                              \
    const int sr = tid >> 2;                                                       \
    const int sc = (tid & 3) * 8;                                                  \
    const bf16_t* gA0 = A_PTR  + (size_t)min(row0 + sr,      M_ROWS - 1) * (K_DIM) + sc; \
    const bf16_t* gA1 = A_PTR  + (size_t)min(row0 + sr + 64, M_ROWS - 1) * (K_DIM) + sc; \
    const bf16_t* gB0 = WT_PTR + (size_t)(col0 + sr) * (K_DIM) + sc;               \
    const bf16_t* gB1 = WT_PTR + (size_t)(col0 + sr + 64) * (K_DIM) + sc;          \
    f32x16 acc[2][2];                                                              \
    _Pragma("unroll")                                                              \
    for (int i = 0; i < 2; i++)                                                    \
        _Pragma("unroll")                                                          \
        for (int j = 0; j < 2; j++)                                                \
            _Pragma("unroll")                                                      \
            for (int r = 0; r < 16; r++) acc[i][j][r] = 0.f;                       \
    bf16x8 pa0 = *(const bf16x8*)gA0;                                              \
    bf16x8 pa1 = *(const bf16x8*)gA1;                                              \
    bf16x8 pb0 = *(const bf16x8*)gB0;                                              \
    bf16x8 pb1 = *(const bf16x8*)gB1;                                              \
    const int nIter = (K_DIM) >> 5;                                                \
    for (int it = 0; it < nIter; it++) {                                           \
        const int cur = it & 1;                                                    \
        *(bf16x8*)&As[cur][sr][sc]      = pa0;                                     \
        *(bf16x8*)&As[cur][sr + 64][sc] = pa1;                                     \
        *(bf16x8*)&Bs[cur][sr][sc]      = pb0;                                     \
        *(bf16x8*)&Bs[cur][sr + 64][sc] = pb1;                                     \
        __syncthreads();                                                           \
        if (it + 1 < nIter) {                                                      \
            int ko = (it + 1) << 5;                                                \
            pa0 = *(const bf16x8*)(gA0 + ko);                                      \
            pa1 = *(const bf16x8*)(gA1 + ko);                                      \
            pb0 = *(const bf16x8*)(gB0 + ko);                                      \
            pb1 = *(const bf16x8*)(gB1 + ko);                                      \
        }                                                                          \
        _Pragma("unroll")                                                          \
        for (int kh = 0; kh < 2; kh++) {                                           \
            bf16x8 a0 = *(const bf16x8*)&As[cur][wr + l31     ][kh * 16 + lh8];    \
            bf16x8 a1 = *(const bf16x8*)&As[cur][wr + 32 + l31][kh * 16 + lh8];    \
            bf16x8 b0 = *(const bf16x8*)&Bs[cur][wc + l31     ][kh * 16 + lh8];    \
            bf16x8 b1 = *(const bf16x8*)&Bs[cur][wc + 32 + l31][kh * 16 + lh8];    \
            acc[0][0] = __builtin_amdgcn_mfma_f32_32x32x16_bf16(a0, b0, acc[0][0], 0, 0, 0); \
            acc[0][1] = __builtin_amdgcn_mfma_f32_32x32x16_bf16(a0, b1, acc[0][1], 0, 0, 0); \
            acc[1][0] = __builtin_amdgcn_mfma_f32_32x32x16_bf16(a1, b0, acc[1][0], 0, 0, 0); \
            acc[1][1] = __builtin_amdgcn_mfma_f32_32x32x16_bf16(a1, b1, acc[1][1], 0, 0, 0); \
        }                                                                          \
    }                                                                              \
    EPILOGUE

// 128x64 tile, BK=32. 4 row-waves (wave w = rows w*32..+31, all 64 cols),
// acc[2] of 32x32, LDS 30KB -> 5 blocks/CU, ~2x grid for N=512 GEMMs.
#define GEMM64_CORE(A_PTR, WT_PTR, K_DIM, EPILOGUE)                                \
    const int tid  = threadIdx.x;                                                  \
    const int wave = tid >> 6;                                                     \
    const int lane = tid & 63;                                                     \
    const int l31  = lane & 31;                                                    \
    const int lh8  = (lane >> 5) * 8;                                              \
    const int wr   = wave * 32;                                                    \
    const int sr = tid >> 2;                                                       \
    const int sc = (tid & 3) * 8;                                                  \
    const bf16_t* gA0 = A_PTR  + (size_t)min(row0 + sr,      M_ROWS - 1) * (K_DIM) + sc; \
    const bf16_t* gA1 = A_PTR  + (size_t)min(row0 + sr + 64, M_ROWS - 1) * (K_DIM) + sc; \
    const bf16_t* gB0 = WT_PTR + (size_t)(col0 + sr) * (K_DIM) + sc;               \
    f32x16 acc[2];                                                                 \
    _Pragma("unroll")                                                              \
    for (int j = 0; j < 2; j++)                                                    \
        _Pragma("unroll")                                                          \
        for (int r = 0; r < 16; r++) acc[j][r] = 0.f;                              \
    bf16x8 pa0 = *(const bf16x8*)gA0;                                              \
    bf16x8 pa1 = *(const bf16x8*)gA1;                                              \
    bf16x8 pb0 = *(const bf16x8*)gB0;                                              \
    const int nIter = (K_DIM) >> 5;                                                \
    for (int it = 0; it < nIter; it++) {                                           \
        const int cur = it & 1;                                                    \
        *(bf16x8*)&As[cur][sr][sc]      = pa0;                                     \
        *(bf16x8*)&As[cur][sr + 64][sc] = pa1;                                     \
        *(bf16x8*)&Bs[cur][sr][sc]      = pb0;                                     \
        __syncthreads();                                                           \
        if (it + 1 < nIter) {                                                      \
            int ko = (it + 1) << 5;                                                \
            pa0 = *(const bf16x8*)(gA0 + ko);                                      \
            pa1 = *(const bf16x8*)(gA1 + ko);                                      \
            pb0 = *(const bf16x8*)(gB0 + ko);                                      \
        }                                                                          \
        _Pragma("unroll")                                                          \
        for (int kh = 0; kh < 2; kh++) {                                           \
            bf16x8 a0 = *(const bf16x8*)&As[cur][wr + l31][kh * 16 + lh8];         \
            bf16x8 b0 = *(const bf16x8*)&Bs[cur][l31     ][kh * 16 + lh8];         \
            bf16x8 b1 = *(const bf16x8*)&Bs[cur][32 + l31][kh * 16 + lh8];         \
            acc[0] = __builtin_amdgcn_mfma_f32_32x32x16_bf16(a0, b0, acc[0], 0, 0, 0); \
            acc[1] = __builtin_amdgcn_mfma_f32_32x32x16_bf16(a0, b1, acc[1], 0, 0, 0); \
        }                                                                          \
    }                                                                              \
    EPILOGUE

// generic 128x128 GEMM (FFN1): C[M,N] = A @ Wt^T + bias, optional ReLU.
template<typename OT, bool RELU, int KD>
__global__ __launch_bounds__(256)
void gemm128_kernel(const bf16_t* __restrict__ A, const bf16_t* __restrict__ Wt,
                    const float* __restrict__ bias, OT* __restrict__ Cout, int N) {
    __shared__ bf16_t As[2][128][40];
    __shared__ bf16_t Bs[2][128][40];
    const int wg = swz_flat();
    const int NY = gridDim.y;
    const int row0 = (wg / NY) * 128;
    const int col0 = (wg % NY) * 128;
    GEMM_CORE(A, Wt, KD,
        {
            _Pragma("unroll")
            for (int i = 0; i < 2; i++)
                _Pragma("unroll")
                for (int j = 0; j < 2; j++) {
                    int col = col0 + wc + j * 32 + l31;
                    float bcol = bias[col];
                    _Pragma("unroll")
                    for (int reg = 0; reg < 16; reg++) {
                        int row = row0 + wr + i * 32 + (reg & 3) + 8 * (reg >> 2) + 4 * (lane >> 5);
                        if (row < M_ROWS) {
                            float v = acc[i][j][reg] + bcol;
                            if (RELU) v = fmaxf(v, 0.f);
                            store_c(Cout + (size_t)row * N + col, v);
                        }
                    }
                }
        }
    )
}

// generic 128x64 GEMM (attn-out, FFN2)
template<typename OT, bool RELU, int KD>
__global__ __launch_bounds__(256)
void gemm64_kernel(const bf16_t* __restrict__ A, const bf16_t* __restrict__ Wt,
                   const float* __restrict__ bias, OT* __restrict__ Cout, int N) {
    __shared__ bf16_t As[2][128][40];
    __shared__ bf16_t Bs[2][64][40];
    const int wg = swz_flat();
    const int NY = gridDim.y;
    const int row0 = (wg / NY) * 128;
    const int col0 = (wg % NY) * 64;
    GEMM64_CORE(A, Wt, KD,
        {
            _Pragma("unroll")
            for (int j = 0; j < 2; j++) {
                int col = col0 + j * 32 + l31;
                float bcol = bias[col];
                _Pragma("unroll")
                for (int reg = 0; reg < 16; reg++) {
                    int row = row0 + wr + (reg & 3) + 8 * (reg >> 2) + 4 * (lane >> 5);
                    if (row < M_ROWS) {
                        float v = acc[j][reg] + bcol;
                        if (RELU) v = fmaxf(v, 0.f);
                        store_c(Cout + (size_t)row * N + col, v);
                    }
                }
            }
        }
    )
}

// merged value (+src_bf A) and oa (+q A) GEMM, 128x64 tiles:
// col tile by<8 -> value (col0=by*64), else oa (col0=(by-8)*64)
__global__ __launch_bounds__(256)
void gemm_voa_kernel(const bf16_t* __restrict__ src_bf, const bf16_t* __restrict__ q,
                     const bf16_t* __restrict__ wt_val, const bf16_t* __restrict__ wt_oa,
                     const float* __restrict__ b_val, const float* __restrict__ bias_oa,
                     bf16_t* __restrict__ value, float* __restrict__ oa) {
    __shared__ bf16_t As[2][128][40];
    __shared__ bf16_t Bs[2][64][40];
    const int wg = swz_flat();                // grid = MT x 14
    const int by = wg % 14;
    const bool isV  = by < 8;
    const int col0  = (isV ? by : by - 8) * 64;
    const int row0  = (wg / 14) * 128;
    const bf16_t* Ap  = isV ? src_bf : q;
    const bf16_t* Wp  = isV ? wt_val : wt_oa;
    const float* bp   = isV ? b_val : bias_oa;
    GEMM64_CORE(Ap, Wp, 512,
        {
            _Pragma("unroll")
            for (int j = 0; j < 2; j++) {
                int col = col0 + j * 32 + l31;
                float bcol = bp[col];
                _Pragma("unroll")
                for (int reg = 0; reg < 16; reg++) {
                    int row = row0 + wr + (reg & 3) + 8 * (reg >> 2) + 4 * (lane >> 5);
                    if (row < M_ROWS) {
                        float v = acc[j][reg] + bcol;
                        if (isV) value[(size_t)row * 512 + col] = (bf16_t)v;
                        else     oa[(size_t)row * 384 + col] = v;
                    }
                }
            }
        }
    )
}

// ---------------------------------------------------------------- sampling (R9)
// 1 wave per bs-row. lane = (h = lane>>3, sub = lane&7). Softmax fused.
__global__ __launch_bounds__(256)
void sample_kernel(const bf16_t* __restrict__ value, const float* __restrict__ oa,
                   bf16_t* __restrict__ out) {
    __shared__ __align__(16) int sAW[4][2][8][68];   // [wave][addr/wgt][h][c pad]
    const int wave = threadIdx.x >> 6;
    const int lane = threadIdx.x & 63;
    const int h    = lane >> 3;
    const int sub  = lane & 7;
    const int bs   = swz_flat() * 4 + wave;          // grid = 4250 exactly
    const int b    = bs / S_LEN;
    const int s    = bs - b * S_LEN;

    float rx, ry;
    if (s < 6400)      { int i = s;        const float inv = 1.f/80.f; ry = ((i/80) + 0.5f)*inv; rx = ((i%80) + 0.5f)*inv; }
    else if (s < 8000) { int i = s - 6400; const float inv = 1.f/40.f; ry = ((i/40) + 0.5f)*inv; rx = ((i%40) + 0.5f)*inv; }
    else if (s < 8400) { int i = s - 8000; const float inv = 1.f/20.f; ry = ((i/20) + 0.5f)*inv; rx = ((i%20) + 0.5f)*inv; }
    else               { int i = s - 8400; const float inv = 1.f/10.f; ry = ((i/10) + 0.5f)*inv; rx = ((i%10) + 0.5f)*inv; }

    const int WH[4]  = {80, 40, 20, 10};
    const int LST[4] = {0, 6400, 8000, 8400};
    const int ll = sub >> 1;            // both of this lane's pts share a level
    const int W  = WH[ll];
    const int LS = LST[ll];

    const float* row = oa + (size_t)bs * 384;
    float4 o4 = *(const float4*)(row + h * 32 + sub * 4);
    float2 lg = *(const float2*)(row + 256 + h * 16 + sub * 2);

    // fused softmax over 16 logits of head h (8 lanes x 2 logits, xor 1/2/4)
    float mx = fmaxf(lg.x, lg.y);
    mx = fmaxf(mx, __shfl_xor(mx, 1, 64));
    mx = fmaxf(mx, __shfl_xor(mx, 2, 64));
    mx = fmaxf(mx, __shfl_xor(mx, 4, 64));
    float e0 = __expf(lg.x - mx), e1 = __expf(lg.y - mx);
    float sm = e0 + e1;
    sm += __shfl_xor(sm, 1, 64);
    sm += __shfl_xor(sm, 2, 64);
    sm += __shfl_xor(sm, 4, 64);
    float pinv = 1.f / sm;

    #pragma unroll
    for (int t = 0; t < 2; t++) {
        float ox = t ? o4.z : o4.x;
        float oy = t ? o4.w : o4.y;
        float p  = (t ? e1 : e0) * pinv;
        float x = fmaf(rx, (float)W, ox) - 0.5f;
        float y = fmaf(ry, (float)W, oy) - 0.5f;
        float fx = floorf(x), fy = floorf(y);
        float wx = x - fx, wy = y - fy;
        int ix = (int)fx, iy = (int)fy;
        #pragma unroll
        for (int k2 = 0; k2 < 4; k2++) {
            int cx = ix + (k2 & 1);
            int cy = iy + (k2 >> 1);
            float wgt = p * ((k2 & 1) ? wx : 1.f - wx) * ((k2 >> 1) ? wy : 1.f - wy);
            if (cx < 0 || cx >= W || cy < 0 || cy >= W) wgt = 0.f;
            int xc = min(max(cx, 0), W - 1);
            int yc = min(max(cy, 0), W - 1);
            int c = sub * 8 + t * 4 + k2;        // pt = c>>2, corner = c&3
            sAW[wave][0][h][c] = LS + yc * W + xc;
            sAW[wave][1][h][c] = __float_as_int(wgt);
        }
    }
    __syncthreads();

    // main loop: lane owns (h, d-slice); all LDS reads broadcast within group
    const bf16_t* vb = value + ((size_t)b * S_LEN) * 512 + h * 64 + sub * 8;
    f32x2 a01 = {0.f, 0.f}, a23 = {0.f, 0.f}, a45 = {0.f, 0.f}, a67 = {0.f, 0.f};

    #define ACC8(V, WW) {                                                          \
        f32x2 ws; ws[0] = (WW); ws[1] = (WW);                                      \
        f32x2 pv;                                                                  \
        pv[0] = __uint_as_float((V).x << 16);                                      \
        pv[1] = __uint_as_float((V).x & 0xffff0000u); pk_fma(a01, pv, ws);         \
        pv[0] = __uint_as_float((V).y << 16);                                      \
        pv[1] = __uint_as_float((V).y & 0xffff0000u); pk_fma(a23, pv, ws);         \
        pv[0] = __uint_as_float((V).z << 16);                                      \
        pv[1] = __uint_as_float((V).z & 0xffff0000u); pk_fma(a45, pv, ws);         \
        pv[0] = __uint_as_float((V).w << 16);                                      \
        pv[1] = __uint_as_float((V).w & 0xffff0000u); pk_fma(a67, pv, ws); }

    #pragma unroll 2
    for (int c8 = 0; c8 < 64; c8 += 8) {
        int4   ia = *(const int4*)  &sAW[wave][0][h][c8];
        int4   ib = *(const int4*)  &sAW[wave][0][h][c8 + 4];
        float4 wa = *(const float4*)&sAW[wave][1][h][c8];
        float4 wb = *(const float4*)&sAW[wave][1][h][c8 + 4];
        uint4 v0 = *(const uint4*)(vb + (size_t)ia.x * 512);
        uint4 v1 = *(const uint4*)(vb + (size_t)ia.y * 512);
        uint4 v2 = *(const uint4*)(vb + (size_t)ia.z * 512);
        uint4 v3 = *(const uint4*)(vb + (size_t)ia.w * 512);
        uint4 v4 = *(const uint4*)(vb + (size_t)ib.x * 512);
        uint4 v5 = *(const uint4*)(vb + (size_t)ib.y * 512);
        uint4 v6 = *(const uint4*)(vb + (size_t)ib.z * 512);
        uint4 v7 = *(const uint4*)(vb + (size_t)ib.w * 512);
        ACC8(v0, wa.x) ACC8(v1, wa.y) ACC8(v2, wa.z) ACC8(v3, wa.w)
        ACC8(v4, wb.x) ACC8(v5, wb.y) ACC8(v6, wb.z) ACC8(v7, wb.w)
    }
    #undef ACC8

    bf16x8 ov;
    ov[0] = (bf16_t)a01[0]; ov[1] = (bf16_t)a01[1];
    ov[2] = (bf16_t)a23[0]; ov[3] = (bf16_t)a23[1];
    ov[4] = (bf16_t)a45[0]; ov[5] = (bf16_t)a45[1];
    ov[6] = (bf16_t)a67[0]; ov[7] = (bf16_t)a67[1];
    *(bf16x8*)(out + (size_t)bs * 512 + h * 64 + sub * 8) = ov;
}

// ---------------------------------------------------------------- LayerNorm
template<typename INA, typename INB, typename OT>
__global__ __launch_bounds__(256)
void ln_kernel(const INA* __restrict__ Xa, const INB* __restrict__ Xb,
               const float* __restrict__ g, const float* __restrict__ be,
               OT* __restrict__ out, int M) {
    int wave = threadIdx.x >> 6;
    int lane = threadIdx.x & 63;
    int row = blockIdx.x * 4 + wave;
    if (row >= M) return;
    size_t base = (size_t)row * 512;
    float v[8];
    float s = 0.f, sq = 0.f;
    #pragma unroll
    for (int p = 0; p < 2; p++) {
        int idx = p * 256 + lane * 4;
        float4 a4 = load4f(Xa + base + idx);
        float4 b4 = load4f(Xb + base + idx);
        float t0 = a4.x + b4.x, t1 = a4.y + b4.y, t2 = a4.z + b4.z, t3 = a4.w + b4.w;
        v[p*4+0] = t0; v[p*4+1] = t1; v[p*4+2] = t2; v[p*4+3] = t3;
        s  += t0 + t1 + t2 + t3;
        sq += t0*t0 + t1*t1 + t2*t2 + t3*t3;
    }
    #pragma unroll
    for (int off = 32; off > 0; off >>= 1) {
        s  += __shfl_xor(s, off, 64);
        sq += __shfl_xor(sq, off, 64);
    }
    float mean = s * (1.f / 512.f);
    float var  = sq * (1.f / 512.f) - mean * mean;
    float rstd = rsqrtf(var + 1e-5f);
    #pragma unroll
    for (int p = 0; p < 2; p++) {
        int idx = p * 256 + lane * 4;
        #pragma unroll
        for (int j = 0; j < 4; j++) {
            int col = idx + j;
            float o = (v[p*4+j] - mean) * rstd * g[col] + be[col];
            store_c(out + base + col, o);
        }
    }
}

// ---------------------------------------------------------------- launch
extern "C" void kernel_launch(void* const* d_in, const int* in_sizes, int n_in,
                              void* d_out, int out_size, void* d_ws, size_t ws_size,
                              hipStream_t stream) {
    const float* src    = (const float*)d_in[0];
    const float* pos    = (const float*)d_in[1];
    const float* w_off  = (const float*)d_in[2];
    const float* b_off  = (const float*)d_in[3];
    const float* w_attn = (const float*)d_in[4];
    const float* b_attn = (const float*)d_in[5];
    const float* w_val  = (const float*)d_in[6];
    const float* b_val  = (const float*)d_in[7];
    const float* w_out  = (const float*)d_in[8];
    const float* b_out  = (const float*)d_in[9];
    const float* ln1_g  = (const float*)d_in[10];
    const float* ln1_b  = (const float*)d_in[11];
    const float* w1     = (const float*)d_in[12];
    const float* b1     = (const float*)d_in[13];
    const float* w2     = (const float*)d_in[14];
    const float* b2     = (const float*)d_in[15];
    const float* ln2_g  = (const float*)d_in[16];
    const float* ln2_b  = (const float*)d_in[17];

    const int M = M_ROWS;
    char* ws = (char*)d_ws;
    size_t o = 0;
    auto alloc = [&](size_t bytes) { size_t r = o; o += (bytes + 255) & ~(size_t)255; return r; };

    size_t off_q       = alloc((size_t)M * 512 * 2);   // bf16
    size_t off_srcbf   = alloc((size_t)M * 512 * 2);   // bf16
    size_t off_value   = alloc((size_t)M * 512 * 2);   // bf16
    size_t off_sampled = alloc((size_t)M * 512 * 2);   // bf16
    size_t off_oa      = alloc((size_t)M * 384 * 4);   // f32
    size_t off_attnout = alloc((size_t)M * 512 * 2);   // bf16
    size_t off_x       = alloc((size_t)M * 512 * 2);   // bf16
    size_t off_wtval   = alloc((size_t)512 * 512 * 2);
    size_t off_wtoa    = alloc((size_t)384 * 512 * 2);
    size_t off_wtout   = alloc((size_t)512 * 512 * 2);
    size_t off_wtw1    = alloc((size_t)1024 * 512 * 2);
    size_t off_wtw2    = alloc((size_t)512 * 1024 * 2);
    size_t off_boa     = alloc((size_t)384 * 4);

    bf16_t* q        = (bf16_t*)(ws + off_q);
    bf16_t* src_bf   = (bf16_t*)(ws + off_srcbf);
    bf16_t* value    = (bf16_t*)(ws + off_value);
    bf16_t* sampled  = (bf16_t*)(ws + off_sampled);
    float*  oa       = (float*)(ws + off_oa);
    bf16_t* attn_out = (bf16_t*)(ws + off_attnout);
    bf16_t* x        = (bf16_t*)(ws + off_x);
    bf16_t* hidden   = (bf16_t*)(ws + off_sampled);   // alias: sampled+oa dead here
    bf16_t* ffn_out  = (bf16_t*)(ws + off_attnout);   // alias: attn_out dead after ln1
    bf16_t* wt_val   = (bf16_t*)(ws + off_wtval);
    bf16_t* wt_oa    = (bf16_t*)(ws + off_wtoa);
    bf16_t* wt_out   = (bf16_t*)(ws + off_wtout);
    bf16_t* wt_w1    = (bf16_t*)(ws + off_wtw1);
    bf16_t* wt_w2    = (bf16_t*)(ws + off_wtw2);
    float*  bias_oa  = (float*)(ws + off_boa);
    float*  outp     = (float*)d_out;

    prep_kernel<<<dim3(32, 32, 7), 256, 0, stream>>>(
        w_val, w_off, w_attn, w_out, w1, w2, b_off, b_attn,
        wt_val, wt_oa, wt_out, wt_w1, wt_w2, bias_oa);

    add_q_kernel<<<(M * 512 / 4 + 255) / 256, 256, 0, stream>>>(src, pos, q, src_bf, M * 512 / 4);

    const int MT = (M + 127) / 128;   // 133

    gemm_voa_kernel<<<dim3(MT, 14), 256, 0, stream>>>(src_bf, q, wt_val, wt_oa, b_val, bias_oa, value, oa);

    // softmax fused into sample_kernel (oa holds raw logits)
    sample_kernel<<<M / 4, 256, 0, stream>>>(value, oa, sampled);

    gemm64_kernel<bf16_t, false, 512><<<dim3(MT, 8), 256, 0, stream>>>(sampled, wt_out, b_out, attn_out, 512);

    ln_kernel<float, bf16_t, bf16_t><<<(M + 3) / 4, 256, 0, stream>>>(src, attn_out, ln1_g, ln1_b, x, M);

    gemm128_kernel<bf16_t, true, 512><<<dim3(MT, 8), 256, 0, stream>>>(x, wt_w1, b1, hidden, 1024);
    gemm64_kernel<bf16_t, false, 1024><<<dim3(MT, 8), 256, 0, stream>>>(hidden, wt_w2, b2, ffn_out, 512);

    ln_kernel<bf16_t, bf16_t, float><<<(M + 3) / 4, 256, 0, stream>>>(x, ffn_out, ln2_g, ln2_b, outp, M);
}

// Round 4
// 349.640 us; speedup vs baseline: 1.0411x; 1.0254x over previous
//
#include <hip/hip_runtime.h>

// ---------------------------------------------------------------------------
// DeformableTransformer encoder layer, MI355X (gfx950).
// R12: GEMM staging switched from reg-staging (global->VGPR->ds_write) to
// direct __builtin_amdgcn_global_load_lds width=16 (m97 structure: linear
// LDS, dbuf, 1 barrier/K-step). Both-sides 16B-chunk XOR swizzle
// (slot ^= (row>>1)&3): inverse on the per-lane global SOURCE (stays within
// each row's 64B -> coalescing unchanged), forward on ds_read addrs ->
// conflict-free b128 reads (linear [128][32] would be 16-way). LDS 40->32/24KB.
// Sample/LN/add_q/prep and 128x64 tiling (R11) unchanged.
// ---------------------------------------------------------------------------

typedef __bf16 bf16_t;
typedef __bf16 bf16x8 __attribute__((ext_vector_type(8)));
typedef __bf16 bf16x4 __attribute__((ext_vector_type(4)));
typedef float  f32x2  __attribute__((ext_vector_type(2)));
typedef float  f32x4  __attribute__((ext_vector_type(4)));
typedef float  f32x16 __attribute__((ext_vector_type(16)));

#define M_ROWS 17000   // B*S
#define S_LEN  8500

// ---------------------------------------------------------------- helpers
__device__ inline void store_c(float* p, float v)  { *p = v; }
__device__ inline void store_c(bf16_t* p, float v) { *p = (bf16_t)v; }

__device__ inline float4 load4f(const float* p)  { return *(const float4*)p; }
__device__ inline float4 load4f(const bf16_t* p) {
    bf16x4 v = *(const bf16x4*)p;
    return make_float4((float)v[0], (float)v[1], (float)v[2], (float)v[3]);
}

__device__ inline void pk_fma(f32x2& a, f32x2 x, f32x2 y) {
    asm("v_pk_fma_f32 %0, %1, %2, %0" : "+v"(a) : "v"(x), "v"(y));
}

// async global->LDS, 16B/lane; LDS dest = wave-uniform base + lane*16
__device__ __forceinline__ void glds16(const bf16_t* g, bf16_t* l) {
    __builtin_amdgcn_global_load_lds(
        (const __attribute__((address_space(1))) void*)g,
        (__attribute__((address_space(3))) void*)l, 16, 0, 0);
}

// bijective XCD-chunked swizzle (m204 form): contiguous result-range per XCD
__device__ inline int swz_flat() {
    int o   = blockIdx.x + gridDim.x * blockIdx.y;
    int nwg = gridDim.x * gridDim.y;
    int q = nwg >> 3, r = nwg & 7;
    int xcd = o & 7, s = o >> 3;
    return (xcd < r ? xcd * (q + 1) : r * (q + 1) + (xcd - r) * q) + s;
}

// ---------------------------------------------------------------- prep
// z = 0..5: transpose f32 [K][N] -> bf16 [N][K] (32x32 tiles);  z = 6: bias concat
__global__ __launch_bounds__(256)
void prep_kernel(const float* __restrict__ w_val, const float* __restrict__ w_off,
                 const float* __restrict__ w_attn, const float* __restrict__ w_out,
                 const float* __restrict__ w1, const float* __restrict__ w2,
                 const float* __restrict__ b_off, const float* __restrict__ b_attn,
                 bf16_t* __restrict__ wt_val, bf16_t* __restrict__ wt_oa,
                 bf16_t* __restrict__ wt_out, bf16_t* __restrict__ wt_w1,
                 bf16_t* __restrict__ wt_w2, float* __restrict__ bias_oa) {
    int z = blockIdx.z;
    if (z == 6) {
        if (blockIdx.x == 0 && blockIdx.y == 0) {
            for (int i = threadIdx.x; i < 384; i += 256)
                bias_oa[i] = (i < 256) ? b_off[i] : b_attn[i - 256];
        }
        return;
    }
    const float* in; bf16_t* out; int K, N;
    switch (z) {
        case 0: in = w_val;  out = wt_val;                     K = 512;  N = 512;  break;
        case 1: in = w_off;  out = wt_oa;                      K = 512;  N = 256;  break;
        case 2: in = w_attn; out = wt_oa + (size_t)256 * 512;  K = 512;  N = 128;  break;
        case 3: in = w_out;  out = wt_out;                     K = 512;  N = 512;  break;
        case 4: in = w1;     out = wt_w1;                      K = 512;  N = 1024; break;
        default: in = w2;    out = wt_w2;                      K = 1024; N = 512;  break;
    }
    int k0 = blockIdx.x * 32, n0 = blockIdx.y * 32;
    if (k0 >= K || n0 >= N) return;
    __shared__ float s[32][33];
    int tx = threadIdx.x & 31, ty = threadIdx.x >> 5;   // ty 0..7
    #pragma unroll
    for (int i = 0; i < 4; i++)
        s[ty + 8 * i][tx] = in[(size_t)(k0 + ty + 8 * i) * N + n0 + tx];
    __syncthreads();
    #pragma unroll
    for (int i = 0; i < 4; i++)
        out[(size_t)(n0 + ty + 8 * i) * K + k0 + tx] = (bf16_t)s[tx][ty + 8 * i];
}

// ---------------------------------------------------------------- q = src+pos
__global__ __launch_bounds__(256)
void add_q_kernel(const float* __restrict__ a, const float* __restrict__ b,
                  bf16_t* __restrict__ q, bf16_t* __restrict__ src_bf, int n4) {
    int i = blockIdx.x * 256 + threadIdx.x;
    if (i >= n4) return;
    float4 av = *(const float4*)(a + (size_t)i * 4);
    float4 bv = *(const float4*)(b + (size_t)i * 4);
    bf16x4 sv, ov;
    sv[0] = (bf16_t)av.x; sv[1] = (bf16_t)av.y; sv[2] = (bf16_t)av.z; sv[3] = (bf16_t)av.w;
    ov[0] = (bf16_t)(av.x + bv.x);
    ov[1] = (bf16_t)(av.y + bv.y);
    ov[2] = (bf16_t)(av.z + bv.z);
    ov[3] = (bf16_t)(av.w + bv.w);
    *(bf16x4*)(q      + (size_t)i * 4) = ov;
    *(bf16x4*)(src_bf + (size_t)i * 4) = sv;
}

// ---------------------------------------------------------------- GEMM cores
// LDS tile = linear [rows][32] bf16 (64B/row = four 16B chunks). Chunk
// involution: phys_slot = log_slot ^ ((row>>1)&3). gload_lds writes lane
// l at base + l*16 -> (row = base+ (l>>2), slot = l&3); its global source
// chunk = (l&3) ^ ((l>>3)&3)  [= slot ^ key(row), key reduces since bases
// are 16-aligned]. Reads: byte = row*64 + ((L ^ ((l31>>1)&3))<<4),
// L = kh*2 + (lane>>5) -> 8 consecutive rows cover all 32 banks.
// D: col=lane&31, row=(reg&3)+8*(reg>>2)+4*(lane>>5)  [m74/m101 verified].

#define GEMM_SETUP                                                                 \
    const int tid  = threadIdx.x;                                                  \
    const int wave = tid >> 6;                                                     \
    const int lane = tid & 63;                                                     \
    const int l31  = lane & 31;                                                    \
    const int pl   = lane >> 5;                                                    \
    const int kx   = (l31 >> 1) & 3;                                               \
    const int st_r = wave * 32 + (lane >> 2);                                      \
    const int st_c = ((lane & 3) ^ ((lane >> 3) & 3)) * 8;

// 128x128 tile (FFN1): 4 waves as 2x2 of 64x64, 16 MFMA/iter.
#define GEMM128_CORE(A_PTR, WT_PTR, K_DIM, EPILOGUE)                               \
    GEMM_SETUP                                                                     \
    const int wr = (wave >> 1) * 64;                                               \
    const int wc = (wave & 1) * 64;                                                \
    const bf16_t* gsA0 = A_PTR  + (size_t)min(row0 + st_r,      M_ROWS - 1) * (K_DIM) + st_c; \
    const bf16_t* gsA1 = A_PTR  + (size_t)min(row0 + st_r + 16, M_ROWS - 1) * (K_DIM) + st_c; \
    const bf16_t* gsB0 = WT_PTR + (size_t)(col0 + st_r) * (K_DIM) + st_c;          \
    const bf16_t* gsB1 = WT_PTR + (size_t)(col0 + st_r + 16) * (K_DIM) + st_c;     \
    f32x16 acc[2][2];                                                              \
    _Pragma("unroll")                                                              \
    for (int i = 0; i < 2; i++)                                                    \
        _Pragma("unroll")                                                          \
        for (int j = 0; j < 2; j++)                                                \
            _Pragma("unroll")                                                      \
            for (int r = 0; r < 16; r++) acc[i][j][r] = 0.f;                       \
    glds16(gsA0, &As[0][wave * 32][0]);                                            \
    glds16(gsA1, &As[0][wave * 32 + 16][0]);                                       \
    glds16(gsB0, &Bs[0][wave * 32][0]);                                            \
    glds16(gsB1, &Bs[0][wave * 32 + 16][0]);                                       \
    const int nIter = (K_DIM) >> 5;                                                \
    for (int it = 0; it < nIter; it++) {                                           \
        const int cur = it & 1;                                                    \
        __syncthreads();                                                           \
        if (it + 1 < nIter) {                                                      \
            const int ko = (it + 1) << 5;                                          \
            glds16(gsA0 + ko, &As[cur ^ 1][wave * 32][0]);                         \
            glds16(gsA1 + ko, &As[cur ^ 1][wave * 32 + 16][0]);                    \
            glds16(gsB0 + ko, &Bs[cur ^ 1][wave * 32][0]);                         \
            glds16(gsB1 + ko, &Bs[cur ^ 1][wave * 32 + 16][0]);                    \
        }                                                                          \
        const char* Ab = (const char*)&As[cur][0][0];                              \
        const char* Bb = (const char*)&Bs[cur][0][0];                              \
        _Pragma("unroll")                                                          \
        for (int kh = 0; kh < 2; kh++) {                                           \
            const int sA = ((kh * 2 + pl) ^ kx) << 4;                              \
            bf16x8 a0 = *(const bf16x8*)(Ab + ((wr      + l31) << 6) + sA);        \
            bf16x8 a1 = *(const bf16x8*)(Ab + ((wr + 32 + l31) << 6) + sA);        \
            bf16x8 b0 = *(const bf16x8*)(Bb + ((wc      + l31) << 6) + sA);        \
            bf16x8 b1 = *(const bf16x8*)(Bb + ((wc + 32 + l31) << 6) + sA);        \
            acc[0][0] = __builtin_amdgcn_mfma_f32_32x32x16_bf16(a0, b0, acc[0][0], 0, 0, 0); \
            acc[0][1] = __builtin_amdgcn_mfma_f32_32x32x16_bf16(a0, b1, acc[0][1], 0, 0, 0); \
            acc[1][0] = __builtin_amdgcn_mfma_f32_32x32x16_bf16(a1, b0, acc[1][0], 0, 0, 0); \
            acc[1][1] = __builtin_amdgcn_mfma_f32_32x32x16_bf16(a1, b1, acc[1][1], 0, 0, 0); \
        }                                                                          \
    }                                                                              \
    EPILOGUE

// 128x64 tile (attn-out, FFN2, voa): wave w = rows w*32..+31, all 64 cols.
#define GEMM64_CORE(A_PTR, WT_PTR, K_DIM, EPILOGUE)                                \
    GEMM_SETUP                                                                     \
    const int wr    = wave * 32;                                                   \
    const int st_rB = wave * 16 + (lane >> 2);                                     \
    const bf16_t* gsA0 = A_PTR  + (size_t)min(row0 + st_r,      M_ROWS - 1) * (K_DIM) + st_c; \
    const bf16_t* gsA1 = A_PTR  + (size_t)min(row0 + st_r + 16, M_ROWS - 1) * (K_DIM) + st_c; \
    const bf16_t* gsB0 = WT_PTR + (size_t)(col0 + st_rB) * (K_DIM) + st_c;         \
    f32x16 acc[2];                                                                 \
    _Pragma("unroll")                                                              \
    for (int j = 0; j < 2; j++)                                                    \
        _Pragma("unroll")                                                          \
        for (int r = 0; r < 16; r++) acc[j][r] = 0.f;                              \
    glds16(gsA0, &As[0][wave * 32][0]);                                            \
    glds16(gsA1, &As[0][wave * 32 + 16][0]);                                       \
    glds16(gsB0, &Bs[0][wave * 16][0]);                                            \
    const int nIter = (K_DIM) >> 5;                                                \
    for (int it = 0; it < nIter; it++) {                                           \
        const int cur = it & 1;                                                    \
        __syncthreads();                                                           \
        if (it + 1 < nIter) {                                                      \
            const int ko = (it + 1) << 5;                                          \
            glds16(gsA0 + ko, &As[cur ^ 1][wave * 32][0]);                         \
            glds16(gsA1 + ko, &As[cur ^ 1][wave * 32 + 16][0]);                    \
            glds16(gsB0 + ko, &Bs[cur ^ 1][wave * 16][0]);                         \
        }                                                                          \
        const char* Ab = (const char*)&As[cur][0][0];                              \
        const char* Bb = (const char*)&Bs[cur][0][0];                              \
        _Pragma("unroll")                                                          \
        for (int kh = 0; kh < 2; kh++) {                                           \
            const int sA = ((kh * 2 + pl) ^ kx) << 4;                              \
            bf16x8 a0 = *(const bf16x8*)(Ab + ((wr + l31) << 6) + sA);             \
            bf16x8 b0 = *(const bf16x8*)(Bb + ((     l31) << 6) + sA);             \
            bf16x8 b1 = *(const bf16x8*)(Bb + ((32 + l31) << 6) + sA);             \
            acc[0] = __builtin_amdgcn_mfma_f32_32x32x16_bf16(a0, b0, acc[0], 0, 0, 0); \
            acc[1] = __builtin_amdgcn_mfma_f32_32x32x16_bf16(a0, b1, acc[1], 0, 0, 0); \
        }                                                                          \
    }                                                                              \
    EPILOGUE

// generic 128x128 GEMM (FFN1): C[M,N] = A @ Wt^T + bias, optional ReLU.
template<typename OT, bool RELU, int KD>
__global__ __launch_bounds__(256)
void gemm128_kernel(const bf16_t* __restrict__ A, const bf16_t* __restrict__ Wt,
                    const float* __restrict__ bias, OT* __restrict__ Cout, int N) {
    __shared__ bf16_t As[2][128][32];
    __shared__ bf16_t Bs[2][128][32];
    const int wg = swz_flat();
    const int NY = gridDim.y;
    const int row0 = (wg / NY) * 128;
    const int col0 = (wg % NY) * 128;
    GEMM128_CORE(A, Wt, KD,
        {
            _Pragma("unroll")
            for (int i = 0; i < 2; i++)
                _Pragma("unroll")
                for (int j = 0; j < 2; j++) {
                    int col = col0 + wc + j * 32 + l31;
                    float bcol = bias[col];
                    _Pragma("unroll")
                    for (int reg = 0; reg < 16; reg++) {
                        int row = row0 + wr + i * 32 + (reg & 3) + 8 * (reg >> 2) + 4 * (lane >> 5);
                        if (row < M_ROWS) {
                            float v = acc[i][j][reg] + bcol;
                            if (RELU) v = fmaxf(v, 0.f);
                            store_c(Cout + (size_t)row * N + col, v);
                        }
                    }
                }
        }
    )
}

// generic 128x64 GEMM (attn-out, FFN2)
template<typename OT, bool RELU, int KD>
__global__ __launch_bounds__(256)
void gemm64_kernel(const bf16_t* __restrict__ A, const bf16_t* __restrict__ Wt,
                   const float* __restrict__ bias, OT* __restrict__ Cout, int N) {
    __shared__ bf16_t As[2][128][32];
    __shared__ bf16_t Bs[2][64][32];
    const int wg = swz_flat();
    const int NY = gridDim.y;
    const int row0 = (wg / NY) * 128;
    const int col0 = (wg % NY) * 64;
    GEMM64_CORE(A, Wt, KD,
        {
            _Pragma("unroll")
            for (int j = 0; j < 2; j++) {
                int col = col0 + j * 32 + l31;
                float bcol = bias[col];
                _Pragma("unroll")
                for (int reg = 0; reg < 16; reg++) {
                    int row = row0 + wr + (reg & 3) + 8 * (reg >> 2) + 4 * (lane >> 5);
                    if (row < M_ROWS) {
                        float v = acc[j][reg] + bcol;
                        if (RELU) v = fmaxf(v, 0.f);
                        store_c(Cout + (size_t)row * N + col, v);
                    }
                }
            }
        }
    )
}

// merged value (+src_bf A) and oa (+q A) GEMM, 128x64 tiles:
// col tile by<8 -> value (col0=by*64), else oa (col0=(by-8)*64)
__global__ __launch_bounds__(256)
void gemm_voa_kernel(const bf16_t* __restrict__ src_bf, const bf16_t* __restrict__ q,
                     const bf16_t* __restrict__ wt_val, const bf16_t* __restrict__ wt_oa,
                     const float* __restrict__ b_val, const float* __restrict__ bias_oa,
                     bf16_t* __restrict__ value, float* __restrict__ oa) {
    __shared__ bf16_t As[2][128][32];
    __shared__ bf16_t Bs[2][64][32];
    const int wg = swz_flat();                // grid = MT x 14
    const int by = wg % 14;
    const bool isV  = by < 8;
    const int col0  = (isV ? by : by - 8) * 64;
    const int row0  = (wg / 14) * 128;
    const bf16_t* Ap  = isV ? src_bf : q;
    const bf16_t* Wp  = isV ? wt_val : wt_oa;
    const float* bp   = isV ? b_val : bias_oa;
    GEMM64_CORE(Ap, Wp, 512,
        {
            _Pragma("unroll")
            for (int j = 0; j < 2; j++) {
                int col = col0 + j * 32 + l31;
                float bcol = bp[col];
                _Pragma("unroll")
                for (int reg = 0; reg < 16; reg++) {
                    int row = row0 + wr + (reg & 3) + 8 * (reg >> 2) + 4 * (lane >> 5);
                    if (row < M_ROWS) {
                        float v = acc[j][reg] + bcol;
                        if (isV) value[(size_t)row * 512 + col] = (bf16_t)v;
                        else     oa[(size_t)row * 384 + col] = v;
                    }
                }
            }
        }
    )
}

// ---------------------------------------------------------------- sampling (R9)
// 1 wave per bs-row. lane = (h = lane>>3, sub = lane&7). Softmax fused.
__global__ __launch_bounds__(256)
void sample_kernel(const bf16_t* __restrict__ value, const float* __restrict__ oa,
                   bf16_t* __restrict__ out) {
    __shared__ __align__(16) int sAW[4][2][8][68];   // [wave][addr/wgt][h][c pad]
    const int wave = threadIdx.x >> 6;
    const int lane = threadIdx.x & 63;
    const int h    = lane >> 3;
    const int sub  = lane & 7;
    const int bs   = swz_flat() * 4 + wave;          // grid = 4250 exactly
    const int b    = bs / S_LEN;
    const int s    = bs - b * S_LEN;

    float rx, ry;
    if (s < 6400)      { int i = s;        const float inv = 1.f/80.f; ry = ((i/80) + 0.5f)*inv; rx = ((i%80) + 0.5f)*inv; }
    else if (s < 8000) { int i = s - 6400; const float inv = 1.f/40.f; ry = ((i/40) + 0.5f)*inv; rx = ((i%40) + 0.5f)*inv; }
    else if (s < 8400) { int i = s - 8000; const float inv = 1.f/20.f; ry = ((i/20) + 0.5f)*inv; rx = ((i%20) + 0.5f)*inv; }
    else               { int i = s - 8400; const float inv = 1.f/10.f; ry = ((i/10) + 0.5f)*inv; rx = ((i%10) + 0.5f)*inv; }

    const int WH[4]  = {80, 40, 20, 10};
    const int LST[4] = {0, 6400, 8000, 8400};
    const int ll = sub >> 1;            // both of this lane's pts share a level
    const int W  = WH[ll];
    const int LS = LST[ll];

    const float* row = oa + (size_t)bs * 384;
    float4 o4 = *(const float4*)(row + h * 32 + sub * 4);
    float2 lg = *(const float2*)(row + 256 + h * 16 + sub * 2);

    // fused softmax over 16 logits of head h (8 lanes x 2 logits, xor 1/2/4)
    float mx = fmaxf(lg.x, lg.y);
    mx = fmaxf(mx, __shfl_xor(mx, 1, 64));
    mx = fmaxf(mx, __shfl_xor(mx, 2, 64));
    mx = fmaxf(mx, __shfl_xor(mx, 4, 64));
    float e0 = __expf(lg.x - mx), e1 = __expf(lg.y - mx);
    float sm = e0 + e1;
    sm += __shfl_xor(sm, 1, 64);
    sm += __shfl_xor(sm, 2, 64);
    sm += __shfl_xor(sm, 4, 64);
    float pinv = 1.f / sm;

    #pragma unroll
    for (int t = 0; t < 2; t++) {
        float ox = t ? o4.z : o4.x;
        float oy = t ? o4.w : o4.y;
        float p  = (t ? e1 : e0) * pinv;
        float x = fmaf(rx, (float)W, ox) - 0.5f;
        float y = fmaf(ry, (float)W, oy) - 0.5f;
        float fx = floorf(x), fy = floorf(y);
        float wx = x - fx, wy = y - fy;
        int ix = (int)fx, iy = (int)fy;
        #pragma unroll
        for (int k2 = 0; k2 < 4; k2++) {
            int cx = ix + (k2 & 1);
            int cy = iy + (k2 >> 1);
            float wgt = p * ((k2 & 1) ? wx : 1.f - wx) * ((k2 >> 1) ? wy : 1.f - wy);
            if (cx < 0 || cx >= W || cy < 0 || cy >= W) wgt = 0.f;
            int xc = min(max(cx, 0), W - 1);
            int yc = min(max(cy, 0), W - 1);
            int c = sub * 8 + t * 4 + k2;        // pt = c>>2, corner = c&3
            sAW[wave][0][h][c] = LS + yc * W + xc;
            sAW[wave][1][h][c] = __float_as_int(wgt);
        }
    }
    __syncthreads();

    // main loop: lane owns (h, d-slice); all LDS reads broadcast within group
    const bf16_t* vb = value + ((size_t)b * S_LEN) * 512 + h * 64 + sub * 8;
    f32x2 a01 = {0.f, 0.f}, a23 = {0.f, 0.f}, a45 = {0.f, 0.f}, a67 = {0.f, 0.f};

    #define ACC8(V, WW) {                                                          \
        f32x2 ws; ws[0] = (WW); ws[1] = (WW);                                      \
        f32x2 pv;                                                                  \
        pv[0] = __uint_as_float((V).x << 16);                                      \
        pv[1] = __uint_as_float((V).x & 0xffff0000u); pk_fma(a01, pv, ws);         \
        pv[0] = __uint_as_float((V).y << 16);                                      \
        pv[1] = __uint_as_float((V).y & 0xffff0000u); pk_fma(a23, pv, ws);         \
        pv[0] = __uint_as_float((V).z << 16);                                      \
        pv[1] = __uint_as_float((V).z & 0xffff0000u); pk_fma(a45, pv, ws);         \
        pv[0] = __uint_as_float((V).w << 16);                                      \
        pv[1] = __uint_as_float((V).w & 0xffff0000u); pk_fma(a67, pv, ws); }

    #pragma unroll 2
    for (int c8 = 0; c8 < 64; c8 += 8) {
        int4   ia = *(const int4*)  &sAW[wave][0][h][c8];
        int4   ib = *(const int4*)  &sAW[wave][0][h][c8 + 4];
        float4 wa = *(const float4*)&sAW[wave][1][h][c8];
        float4 wb = *(const float4*)&sAW[wave][1][h][c8 + 4];
        uint4 v0 = *(const uint4*)(vb + (size_t)ia.x * 512);
        uint4 v1 = *(const uint4*)(vb + (size_t)ia.y * 512);
        uint4 v2 = *(const uint4*)(vb + (size_t)ia.z * 512);
        uint4 v3 = *(const uint4*)(vb + (size_t)ia.w * 512);
        uint4 v4 = *(const uint4*)(vb + (size_t)ib.x * 512);
        uint4 v5 = *(const uint4*)(vb + (size_t)ib.y * 512);
        uint4 v6 = *(const uint4*)(vb + (size_t)ib.z * 512);
        uint4 v7 = *(const uint4*)(vb + (size_t)ib.w * 512);
        ACC8(v0, wa.x) ACC8(v1, wa.y) ACC8(v2, wa.z) ACC8(v3, wa.w)
        ACC8(v4, wb.x) ACC8(v5, wb.y) ACC8(v6, wb.z) ACC8(v7, wb.w)
    }
    #undef ACC8

    bf16x8 ov;
    ov[0] = (bf16_t)a01[0]; ov[1] = (bf16_t)a01[1];
    ov[2] = (bf16_t)a23[0]; ov[3] = (bf16_t)a23[1];
    ov[4] = (bf16_t)a45[0]; ov[5] = (bf16_t)a45[1];
    ov[6] = (bf16_t)a67[0]; ov[7] = (bf16_t)a67[1];
    *(bf16x8*)(out + (size_t)bs * 512 + h * 64 + sub * 8) = ov;
}

// ---------------------------------------------------------------- LayerNorm
template<typename INA, typename INB, typename OT>
__global__ __launch_bounds__(256)
void ln_kernel(const INA* __restrict__ Xa, const INB* __restrict__ Xb,
               const float* __restrict__ g, const float* __restrict__ be,
               OT* __restrict__ out, int M) {
    int wave = threadIdx.x >> 6;
    int lane = threadIdx.x & 63;
    int row = blockIdx.x * 4 + wave;
    if (row >= M) return;
    size_t base = (size_t)row * 512;
    float v[8];
    float s = 0.f, sq = 0.f;
    #pragma unroll
    for (int p = 0; p < 2; p++) {
        int idx = p * 256 + lane * 4;
        float4 a4 = load4f(Xa + base + idx);
        float4 b4 = load4f(Xb + base + idx);
        float t0 = a4.x + b4.x, t1 = a4.y + b4.y, t2 = a4.z + b4.z, t3 = a4.w + b4.w;
        v[p*4+0] = t0; v[p*4+1] = t1; v[p*4+2] = t2; v[p*4+3] = t3;
        s  += t0 + t1 + t2 + t3;
        sq += t0*t0 + t1*t1 + t2*t2 + t3*t3;
    }
    #pragma unroll
    for (int off = 32; off > 0; off >>= 1) {
        s  += __shfl_xor(s, off, 64);
        sq += __shfl_xor(sq, off, 64);
    }
    float mean = s * (1.f / 512.f);
    float var  = sq * (1.f / 512.f) - mean * mean;
    float rstd = rsqrtf(var + 1e-5f);
    #pragma unroll
    for (int p = 0; p < 2; p++) {
        int idx = p * 256 + lane * 4;
        #pragma unroll
        for (int j = 0; j < 4; j++) {
            int col = idx + j;
            float o = (v[p*4+j] - mean) * rstd * g[col] + be[col];
            store_c(out + base + col, o);
        }
    }
}

// ---------------------------------------------------------------- launch
extern "C" void kernel_launch(void* const* d_in, const int* in_sizes, int n_in,
                              void* d_out, int out_size, void* d_ws, size_t ws_size,
                              hipStream_t stream) {
    const float* src    = (const float*)d_in[0];
    const float* pos    = (const float*)d_in[1];
    const float* w_off  = (const float*)d_in[2];
    const float* b_off  = (const float*)d_in[3];
    const float* w_attn = (const float*)d_in[4];
    const float* b_attn = (const float*)d_in[5];
    const float* w_val  = (const float*)d_in[6];
    const float* b_val  = (const float*)d_in[7];
    const float* w_out  = (const float*)d_in[8];
    const float* b_out  = (const float*)d_in[9];
    const float* ln1_g  = (const float*)d_in[10];
    const float* ln1_b  = (const float*)d_in[11];
    const float* w1     = (const float*)d_in[12];
    const float* b1     = (const float*)d_in[13];
    const float* w2     = (const float*)d_in[14];
    const float* b2     = (const float*)d_in[15];
    const float* ln2_g  = (const float*)d_in[16];
    const float* ln2_b  = (const float*)d_in[17];

    const int M = M_ROWS;
    char* ws = (char*)d_ws;
    size_t o = 0;
    auto alloc = [&](size_t bytes) { size_t r = o; o += (bytes + 255) & ~(size_t)255; return r; };

    size_t off_q       = alloc((size_t)M * 512 * 2);   // bf16
    size_t off_srcbf   = alloc((size_t)M * 512 * 2);   // bf16
    size_t off_value   = alloc((size_t)M * 512 * 2);   // bf16
    size_t off_sampled = alloc((size_t)M * 512 * 2);   // bf16
    size_t off_oa      = alloc((size_t)M * 384 * 4);   // f32
    size_t off_attnout = alloc((size_t)M * 512 * 2);   // bf16
    size_t off_x       = alloc((size_t)M * 512 * 2);   // bf16
    size_t off_wtval   = alloc((size_t)512 * 512 * 2);
    size_t off_wtoa    = alloc((size_t)384 * 512 * 2);
    size_t off_wtout   = alloc((size_t)512 * 512 * 2);
    size_t off_wtw1    = alloc((size_t)1024 * 512 * 2);
    size_t off_wtw2    = alloc((size_t)512 * 1024 * 2);
    size_t off_boa     = alloc((size_t)384 * 4);

    bf16_t* q        = (bf16_t*)(ws + off_q);
    bf16_t* src_bf   = (bf16_t*)(ws + off_srcbf);
    bf16_t* value    = (bf16_t*)(ws + off_value);
    bf16_t* sampled  = (bf16_t*)(ws + off_sampled);
    float*  oa       = (float*)(ws + off_oa);
    bf16_t* attn_out = (bf16_t*)(ws + off_attnout);
    bf16_t* x        = (bf16_t*)(ws + off_x);
    bf16_t* hidden   = (bf16_t*)(ws + off_sampled);   // alias: sampled+oa dead here
    bf16_t* ffn_out  = (bf16_t*)(ws + off_attnout);   // alias: attn_out dead after ln1
    bf16_t* wt_val   = (bf16_t*)(ws + off_wtval);
    bf16_t* wt_oa    = (bf16_t*)(ws + off_wtoa);
    bf16_t* wt_out   = (bf16_t*)(ws + off_wtout);
    bf16_t* wt_w1    = (bf16_t*)(ws + off_wtw1);
    bf16_t* wt_w2    = (bf16_t*)(ws + off_wtw2);
    float*  bias_oa  = (float*)(ws + off_boa);
    float*  outp     = (float*)d_out;

    prep_kernel<<<dim3(32, 32, 7), 256, 0, stream>>>(
        w_val, w_off, w_attn, w_out, w1, w2, b_off, b_attn,
        wt_val, wt_oa, wt_out, wt_w1, wt_w2, bias_oa);

    add_q_kernel<<<(M * 512 / 4 + 255) / 256, 256, 0, stream>>>(src, pos, q, src_bf, M * 512 / 4);

    const int MT = (M + 127) / 128;   // 133

    gemm_voa_kernel<<<dim3(MT, 14), 256, 0, stream>>>(src_bf, q, wt_val, wt_oa, b_val, bias_oa, value, oa);

    // softmax fused into sample_kernel (oa holds raw logits)
    sample_kernel<<<M / 4, 256, 0, stream>>>(value, oa, sampled);

    gemm64_kernel<bf16_t, false, 512><<<dim3(MT, 8), 256, 0, stream>>>(sampled, wt_out, b_out, attn_out, 512);

    ln_kernel<float, bf16_t, bf16_t><<<(M + 3) / 4, 256, 0, stream>>>(src, attn_out, ln1_g, ln1_b, x, M);

    gemm128_kernel<bf16_t, true, 512><<<dim3(MT, 8), 256, 0, stream>>>(x, wt_w1, b1, hidden, 1024);
    gemm64_kernel<bf16_t, false, 1024><<<dim3(MT, 8), 256, 0, stream>>>(hidden, wt_w2, b2, ffn_out, 512);

    ln_kernel<bf16_t, bf16_t, float><<<(M + 3) / 4, 256, 0, stream>>>(x, ffn_out, ln2_g, ln2_b, outp, M);
}